// Round 4
// baseline (989.470 us; speedup 1.0000x reference)
//
#include <hip/hip_runtime.h>
#include <cstdint>
#include <cstddef>

#define N_NODES 50000
#define N_EDGES 1600000
#define D 512
#define MPAD 50048   // 391 * 128, padded M for 128-row GEMM tiles

typedef __attribute__((ext_vector_type(8))) short bf16x8;
typedef __attribute__((ext_vector_type(4))) float f32x4;
typedef __attribute__((ext_vector_type(8))) unsigned short u16x8;
typedef __attribute__((ext_vector_type(4))) unsigned short u16x4;
typedef __attribute__((ext_vector_type(2))) int i32x2;
typedef __attribute__((ext_vector_type(4))) int i32x4;

static __device__ __forceinline__ unsigned short f2bf(float f) {
  unsigned u = __float_as_uint(f);
  u += 0x7fffu + ((u >> 16) & 1u);   // RNE
  return (unsigned short)(u >> 16);
}

// ---------------- convert x (f32 -> bf16) ----------------
__global__ __launch_bounds__(256) void convert_x(const float* __restrict__ x,
                                                 unsigned short* __restrict__ xb) {
  size_t i = ((size_t)blockIdx.x * 256 + threadIdx.x) * 8;
  if (i >= (size_t)N_NODES * D) return;
  const f32x4* f = (const f32x4*)(x + i);
  f32x4 f0 = __builtin_nontemporal_load(f);
  f32x4 f1 = __builtin_nontemporal_load(f + 1);
  u16x8 v;
  v[0] = f2bf(f0[0]); v[1] = f2bf(f0[1]); v[2] = f2bf(f0[2]); v[3] = f2bf(f0[3]);
  v[4] = f2bf(f1[0]); v[5] = f2bf(f1[1]); v[6] = f2bf(f1[2]); v[7] = f2bf(f1[3]);
  *(u16x8*)(xb + i) = v;
}

// ---------------- convert w0,w1 -> wbT[512][1024]: wbT[j][k] = Wcat[k][j] ----------------
__global__ __launch_bounds__(256) void convert_w(const float* __restrict__ w0,
                                                 const float* __restrict__ w1,
                                                 unsigned short* __restrict__ wbT) {
  int idx = blockIdx.x * 256 + threadIdx.x;   // idx = j*1024 + k
  if (idx >= 512 * 1024) return;
  int k = idx & 1023;
  int j = idx >> 10;
  float v = (k < 512) ? w0[k * 512 + j] : w1[(k - 512) * 512 + j];
  wbT[idx] = f2bf(v);
}

// ---------------- histogram of destination rows (NT int4 reads) ----------------
__global__ __launch_bounds__(256) void histogram(const int* __restrict__ r0,
                                                 const int* __restrict__ r1,
                                                 int* __restrict__ c0,
                                                 int* __restrict__ c1) {
  const int nq = N_EDGES / 4;
  int stride = gridDim.x * blockDim.x;
  for (int i = blockIdx.x * blockDim.x + threadIdx.x; i < 2 * nq; i += stride) {
    if (i < nq) {
      i32x4 r = __builtin_nontemporal_load((const i32x4*)r0 + i);
      atomicAdd(&c0[r[0]], 1); atomicAdd(&c0[r[1]], 1);
      atomicAdd(&c0[r[2]], 1); atomicAdd(&c0[r[3]], 1);
    } else {
      i32x4 r = __builtin_nontemporal_load((const i32x4*)r1 + (i - nq));
      atomicAdd(&c1[r[0]], 1); atomicAdd(&c1[r[1]], 1);
      atomicAdd(&c1[r[2]], 1); atomicAdd(&c1[r[3]], 1);
    }
  }
}

// ---------------- exclusive scan, shuffle-based (one block per support) ----------------
__global__ __launch_bounds__(1024) void scan2(const int* __restrict__ cnt0,
                                              const int* __restrict__ cnt1,
                                              int* __restrict__ rp0, int* __restrict__ rp1,
                                              int* __restrict__ cur0, int* __restrict__ cur1) {
  __shared__ int wsum[16];
  __shared__ int stot;
  const int* cnt = (blockIdx.x == 0) ? cnt0 : cnt1;
  int* rp  = (blockIdx.x == 0) ? rp0  : rp1;
  int* cur = (blockIdx.x == 0) ? cur0 : cur1;
  const int t = threadIdx.x;
  const int lane = t & 63;
  const int wave = t >> 6;
  int carry = 0;
  for (int base = 0; base < N_NODES; base += 4096) {
    int idx = base + t * 4;
    int c0 = 0, c1 = 0, c2 = 0, c3 = 0;
    if (idx + 3 < N_NODES) {
      int4 c = *(const int4*)(cnt + idx);
      c0 = c.x; c1 = c.y; c2 = c.z; c3 = c.w;
    } else {
      if (idx     < N_NODES) c0 = cnt[idx];
      if (idx + 1 < N_NODES) c1 = cnt[idx + 1];
      if (idx + 2 < N_NODES) c2 = cnt[idx + 2];
      if (idx + 3 < N_NODES) c3 = cnt[idx + 3];
    }
    int s0 = c0, s01 = s0 + c1, s012 = s01 + c2, tsum = s012 + c3;
    int incl = tsum;
    #pragma unroll
    for (int off = 1; off < 64; off <<= 1) {
      int v = __shfl_up(incl, off, 64);
      if (lane >= off) incl += v;
    }
    if (lane == 63) wsum[wave] = incl;
    __syncthreads();
    if (wave == 0) {
      int v = (lane < 16) ? wsum[lane] : 0;
      int winc = v;
      #pragma unroll
      for (int off = 1; off < 16; off <<= 1) {
        int u = __shfl_up(winc, off, 64);
        if (lane >= off) winc += u;
      }
      if (lane < 16) wsum[lane] = winc - v;   // exclusive
      if (lane == 15) stot = winc;
    }
    __syncthreads();
    int ebase = carry + wsum[wave] + (incl - tsum);
    if (idx     < N_NODES) { rp[idx]     = ebase;        cur[idx]     = ebase; }
    if (idx + 1 < N_NODES) { rp[idx + 1] = ebase + s0;   cur[idx + 1] = ebase + s0; }
    if (idx + 2 < N_NODES) { rp[idx + 2] = ebase + s01;  cur[idx + 2] = ebase + s01; }
    if (idx + 3 < N_NODES) { rp[idx + 3] = ebase + s012; cur[idx + 3] = ebase + s012; }
    carry += stot;
    __syncthreads();
  }
  if (t == 0) rp[N_NODES] = carry;
}

// ---------------- CSR fill: packed (col, val) int2; NT vector reads ----------------
__global__ __launch_bounds__(256) void fill_csr(const int* __restrict__ r0, const int* __restrict__ co0, const float* __restrict__ v0,
                                                const int* __restrict__ r1, const int* __restrict__ co1, const float* __restrict__ v1,
                                                int* __restrict__ cur0, int* __restrict__ cur1,
                                                int2* __restrict__ e0, int2* __restrict__ e1) {
  const int nq = N_EDGES / 4;
  int stride = gridDim.x * blockDim.x;
  for (int i = blockIdx.x * blockDim.x + threadIdx.x; i < 2 * nq; i += stride) {
    if (i < nq) {
      i32x4 r = __builtin_nontemporal_load((const i32x4*)r0 + i);
      i32x4 c = __builtin_nontemporal_load((const i32x4*)co0 + i);
      f32x4 v = __builtin_nontemporal_load((const f32x4*)v0 + i);
      #pragma unroll
      for (int k = 0; k < 4; ++k) {
        int p = atomicAdd(&cur0[r[k]], 1);
        e0[p] = make_int2(c[k], __float_as_int(v[k]));
      }
    } else {
      int j = i - nq;
      i32x4 r = __builtin_nontemporal_load((const i32x4*)r1 + j);
      i32x4 c = __builtin_nontemporal_load((const i32x4*)co1 + j);
      f32x4 v = __builtin_nontemporal_load((const f32x4*)v1 + j);
      #pragma unroll
      for (int k = 0; k < 4; ++k) {
        int p = atomicAdd(&cur1[r[k]], 1);
        e1[p] = make_int2(c[k], __float_as_int(v[k]));
      }
    }
  }
}

// ---------------- SpMM column-pass: active gather set = 25.6 MB per pass ----------------
// PASS p covers cols [p*256, p*256+256). 1 wave = 1 dest row; lane owns 4 cols (8B loads).
// Both supports handled: s[n][c] (sup0) and s[n][512+c] (sup1).
template<int PASS>
__global__ __launch_bounds__(256) void spmm_pass(const unsigned short* __restrict__ xb,
    const int* __restrict__ rp0, const int2* __restrict__ e0,
    const int* __restrict__ rp1, const int2* __restrict__ e1,
    unsigned short* __restrict__ s) {
  const int t = threadIdx.x;
  const int lane = t & 63;
  const int wave = t >> 6;
  const int n = blockIdx.x * 4 + wave;          // grid 12500 * 4 waves = 50000 rows
  const int c0 = PASS * 256 + lane * 4;

  float acc[2][4] = {};

  #pragma unroll
  for (int sup = 0; sup < 2; ++sup) {
    const int* rp = sup ? rp1 : rp0;
    const int2* e = sup ? e1 : e0;
    float* a = acc[sup];
    const int beg = rp[n], end = rp[n + 1];
    int p = beg;
    for (; p + 3 < end; p += 4) {
      i32x2 eA = __builtin_nontemporal_load((const i32x2*)(e + p));
      i32x2 eB = __builtin_nontemporal_load((const i32x2*)(e + p + 1));
      i32x2 eC = __builtin_nontemporal_load((const i32x2*)(e + p + 2));
      i32x2 eD = __builtin_nontemporal_load((const i32x2*)(e + p + 3));
      u16x4 rA = *(const u16x4*)(xb + (size_t)eA[0] * D + c0);
      u16x4 rB = *(const u16x4*)(xb + (size_t)eB[0] * D + c0);
      u16x4 rC = *(const u16x4*)(xb + (size_t)eC[0] * D + c0);
      u16x4 rD = *(const u16x4*)(xb + (size_t)eD[0] * D + c0);
      float vA = __int_as_float(eA[1]), vB = __int_as_float(eB[1]);
      float vC = __int_as_float(eC[1]), vD = __int_as_float(eD[1]);
      #pragma unroll
      for (int i = 0; i < 4; ++i) {
        a[i] += vA * __uint_as_float(((unsigned)rA[i]) << 16);
        a[i] += vB * __uint_as_float(((unsigned)rB[i]) << 16);
        a[i] += vC * __uint_as_float(((unsigned)rC[i]) << 16);
        a[i] += vD * __uint_as_float(((unsigned)rD[i]) << 16);
      }
    }
    for (; p < end; ++p) {
      i32x2 eA = __builtin_nontemporal_load((const i32x2*)(e + p));
      u16x4 rA = *(const u16x4*)(xb + (size_t)eA[0] * D + c0);
      float vA = __int_as_float(eA[1]);
      #pragma unroll
      for (int i = 0; i < 4; ++i)
        a[i] += vA * __uint_as_float(((unsigned)rA[i]) << 16);
    }
  }

  u16x4 o0, o1;
  #pragma unroll
  for (int i = 0; i < 4; ++i) { o0[i] = f2bf(acc[0][i]); o1[i] = f2bf(acc[1][i]); }
  __builtin_nontemporal_store(o0, (u16x4*)(s + (size_t)n * 1024 + c0));
  __builtin_nontemporal_store(o1, (u16x4*)(s + (size_t)n * 1024 + 512 + c0));
}

// ---------------- GEMM: out = relu( s[MPAD][1024] @ Wcat[1024][512] + b ), 2-phase dbuf ----------------
#define BM 128
#define BN 128
#define BK 32

__global__ __launch_bounds__(256) void gemm_out(const unsigned short* __restrict__ s,
                                                const unsigned short* __restrict__ wbT,
                                                const float* __restrict__ bias,
                                                float* __restrict__ out) {
  __shared__ __align__(16) unsigned short As[2][BM * BK];
  __shared__ __align__(16) unsigned short Bs[2][BN * BK];
  const int t = threadIdx.x;
  const int lane = t & 63;
  const int wave = t >> 6;
  const int wm = wave >> 1, wn = wave & 1;
  const int lr = lane & 15;
  const int lk = (lane >> 4) * 8;
  const int m0 = blockIdx.y * BM;
  const int n0 = blockIdx.x * BN;

  f32x4 acc[4][4] = {};
  const int NT = 1024 / BK;   // 32 K-steps

  auto STAGE = [&](int buf, int kt) {
    #pragma unroll
    for (int i = 0; i < 2; ++i) {
      int ch = i * 256 + t;
      int row = ch >> 2;
      int ke = (ch & 3) * 8;
      const unsigned short* ga = s + (size_t)(m0 + row) * 1024 + kt * BK + ke;
      __builtin_amdgcn_global_load_lds(
          (const __attribute__((address_space(1))) unsigned int*)ga,
          (__attribute__((address_space(3))) unsigned int*)(&As[buf][ch * 8]), 16, 0, 0);
      const unsigned short* gb = wbT + (size_t)(n0 + row) * 1024 + kt * BK + ke;
      __builtin_amdgcn_global_load_lds(
          (const __attribute__((address_space(1))) unsigned int*)gb,
          (__attribute__((address_space(3))) unsigned int*)(&Bs[buf][ch * 8]), 16, 0, 0);
    }
  };

  STAGE(0, 0);
  __syncthreads();

  for (int kt = 0; kt < NT; ++kt) {
    const int cur = kt & 1;
    if (kt + 1 < NT) STAGE(cur ^ 1, kt + 1);

    bf16x8 a[4], b[4];
    #pragma unroll
    for (int i = 0; i < 4; ++i)
      a[i] = *(const bf16x8*)&As[cur][(wm * 64 + i * 16 + lr) * BK + lk];
    #pragma unroll
    for (int j = 0; j < 4; ++j)
      b[j] = *(const bf16x8*)&Bs[cur][(wn * 64 + j * 16 + lr) * BK + lk];
    #pragma unroll
    for (int i = 0; i < 4; ++i)
      #pragma unroll
      for (int j = 0; j < 4; ++j)
        acc[i][j] = __builtin_amdgcn_mfma_f32_16x16x32_bf16(a[i], b[j], acc[i][j], 0, 0, 0);
    __syncthreads();
  }

  float bj[4];
  #pragma unroll
  for (int j = 0; j < 4; ++j) bj[j] = bias[n0 + wn * 64 + j * 16 + lr];

  const int orow = (lane >> 4) * 4;
  #pragma unroll
  for (int i = 0; i < 4; ++i) {
    #pragma unroll
    for (int j = 0; j < 4; ++j) {
      #pragma unroll
      for (int r = 0; r < 4; ++r) {
        int row = m0 + wm * 64 + i * 16 + orow + r;
        if (row < N_NODES) {
          int col = n0 + wn * 64 + j * 16 + lr;
          __builtin_nontemporal_store(fmaxf(acc[i][j][r] + bj[j], 0.f),
                                      out + (size_t)row * 512 + col);
        }
      }
    }
  }
}

// ---------------- launch ----------------
extern "C" void kernel_launch(void* const* d_in, const int* in_sizes, int n_in,
                              void* d_out, int out_size, void* d_ws, size_t ws_size,
                              hipStream_t stream) {
  const float* x     = (const float*)d_in[0];
  const float* w0    = (const float*)d_in[1];
  const float* w1    = (const float*)d_in[2];
  const float* bias  = (const float*)d_in[3];
  const float* vals0 = (const float*)d_in[4];
  const float* vals1 = (const float*)d_in[5];
  const int*   rows0 = (const int*)d_in[6];
  const int*   cols0 = (const int*)d_in[7];
  const int*   rows1 = (const int*)d_in[8];
  const int*   cols1 = (const int*)d_in[9];
  float* out = (float*)d_out;

  char* ws = (char*)d_ws;
  size_t off = 0;
  auto alloc = [&](size_t bytes) -> char* {
    char* p = ws + off;
    off += (bytes + 255) & ~(size_t)255;
    return p;
  };
  unsigned short* xb  = (unsigned short*)alloc((size_t)N_NODES * D * 2);   // 51.2 MB
  unsigned short* wbT = (unsigned short*)alloc((size_t)512 * 1024 * 2);    // 1 MB
  unsigned short* s   = (unsigned short*)alloc((size_t)MPAD * 1024 * 2);   // 102.5 MB
  int* rp0  = (int*)alloc((N_NODES + 1) * sizeof(int));
  int* rp1  = (int*)alloc((N_NODES + 1) * sizeof(int));
  int* cur0 = (int*)alloc(N_NODES * sizeof(int));
  int* cur1 = (int*)alloc(N_NODES * sizeof(int));
  int* cnt  = (int*)alloc(2 * N_NODES * sizeof(int));
  int2* e0  = (int2*)alloc((size_t)N_EDGES * sizeof(int2));                // 12.8 MB
  int2* e1  = (int2*)alloc((size_t)N_EDGES * sizeof(int2));                // 12.8 MB

  hipMemsetAsync(cnt, 0, 2 * N_NODES * sizeof(int), stream);
  hipMemsetAsync(s + (size_t)N_NODES * 1024, 0, (size_t)(MPAD - N_NODES) * 1024 * 2, stream);

  convert_x<<<dim3((unsigned)((size_t)N_NODES * D / 8 / 256)), 256, 0, stream>>>(x, xb);
  convert_w<<<dim3(512 * 1024 / 256), 256, 0, stream>>>(w0, w1, wbT);
  histogram<<<2048, 256, 0, stream>>>(rows0, rows1, cnt, cnt + N_NODES);
  scan2<<<2, 1024, 0, stream>>>(cnt, cnt + N_NODES, rp0, rp1, cur0, cur1);
  fill_csr<<<2048, 256, 0, stream>>>(rows0, cols0, vals0, rows1, cols1, vals1,
                                     cur0, cur1, e0, e1);
  spmm_pass<0><<<N_NODES / 4, 256, 0, stream>>>(xb, rp0, e0, rp1, e1, s);
  spmm_pass<1><<<N_NODES / 4, 256, 0, stream>>>(xb, rp0, e0, rp1, e1, s);
  gemm_out<<<dim3(512 / BN, MPAD / BM), 256, 0, stream>>>(s, wbT, bias, out);
}

// Round 5
// 909.347 us; speedup vs baseline: 1.0881x; 1.0881x over previous
//
#include <hip/hip_runtime.h>
#include <cstdint>
#include <cstddef>

#define N_NODES 50000
#define N_EDGES 1600000
#define D 512
#define MPAD 50048   // 391 * 128, padded M for 128-row GEMM tiles
#define NPX 6250     // nodes per XCD dest-range (50000/8)

typedef __attribute__((ext_vector_type(8))) short bf16x8;
typedef __attribute__((ext_vector_type(4))) float f32x4;
typedef __attribute__((ext_vector_type(8))) unsigned short u16x8;
typedef __attribute__((ext_vector_type(2))) int i32x2;
typedef __attribute__((ext_vector_type(4))) int i32x4;

static __device__ __forceinline__ unsigned short f2bf(float f) {
  unsigned u = __float_as_uint(f);
  u += 0x7fffu + ((u >> 16) & 1u);   // RNE
  return (unsigned short)(u >> 16);
}

// ---------------- convert x (f32 -> bf16) ----------------
__global__ __launch_bounds__(256) void convert_x(const float* __restrict__ x,
                                                 unsigned short* __restrict__ xb) {
  size_t i = ((size_t)blockIdx.x * 256 + threadIdx.x) * 8;
  if (i >= (size_t)N_NODES * D) return;
  const f32x4* f = (const f32x4*)(x + i);
  f32x4 f0 = __builtin_nontemporal_load(f);
  f32x4 f1 = __builtin_nontemporal_load(f + 1);
  u16x8 v;
  v[0] = f2bf(f0[0]); v[1] = f2bf(f0[1]); v[2] = f2bf(f0[2]); v[3] = f2bf(f0[3]);
  v[4] = f2bf(f1[0]); v[5] = f2bf(f1[1]); v[6] = f2bf(f1[2]); v[7] = f2bf(f1[3]);
  *(u16x8*)(xb + i) = v;
}

// ---------------- convert w0,w1 -> wbT[512][1024]: wbT[j][k] = Wcat[k][j] ----------------
__global__ __launch_bounds__(256) void convert_w(const float* __restrict__ w0,
                                                 const float* __restrict__ w1,
                                                 unsigned short* __restrict__ wbT) {
  int idx = blockIdx.x * 256 + threadIdx.x;   // idx = j*1024 + k
  if (idx >= 512 * 1024) return;
  int k = idx & 1023;
  int j = idx >> 10;
  float v = (k < 512) ? w0[k * 512 + j] : w1[(k - 512) * 512 + j];
  wbT[idx] = f2bf(v);
}

// ---------------- histogram, XCD-local dest ranges ----------------
// blockIdx%8 = XCD g handles dests [g*NPX, (g+1)*NPX): atomics stay in one L2.
__global__ __launch_bounds__(256) void histogram(const int* __restrict__ r0,
                                                 const int* __restrict__ r1,
                                                 int* __restrict__ c0,
                                                 int* __restrict__ c1) {
  const int nq = N_EDGES / 4;
  const int lo = (int)(blockIdx.x & 7) * NPX;
  const int hi = lo + NPX;
  const int stride = (1024 >> 3) * 256;   // threads per XCD-group
  for (int i = (int)(blockIdx.x >> 3) * 256 + threadIdx.x; i < 2 * nq; i += stride) {
    if (i < nq) {
      i32x4 r = __builtin_nontemporal_load((const i32x4*)r0 + i);
      #pragma unroll
      for (int k = 0; k < 4; ++k)
        if (r[k] >= lo && r[k] < hi) atomicAdd(&c0[r[k]], 1);
    } else {
      i32x4 r = __builtin_nontemporal_load((const i32x4*)r1 + (i - nq));
      #pragma unroll
      for (int k = 0; k < 4; ++k)
        if (r[k] >= lo && r[k] < hi) atomicAdd(&c1[r[k]], 1);
    }
  }
}

// ---------------- exclusive scan, shuffle-based (one block per support) ----------------
__global__ __launch_bounds__(1024) void scan2(const int* __restrict__ cnt0,
                                              const int* __restrict__ cnt1,
                                              int* __restrict__ rp0, int* __restrict__ rp1,
                                              int* __restrict__ cur0, int* __restrict__ cur1) {
  __shared__ int wsum[16];
  __shared__ int stot;
  const int* cnt = (blockIdx.x == 0) ? cnt0 : cnt1;
  int* rp  = (blockIdx.x == 0) ? rp0  : rp1;
  int* cur = (blockIdx.x == 0) ? cur0 : cur1;
  const int t = threadIdx.x;
  const int lane = t & 63;
  const int wave = t >> 6;
  int carry = 0;
  for (int base = 0; base < N_NODES; base += 4096) {
    int idx = base + t * 4;
    int c0 = 0, c1 = 0, c2 = 0, c3 = 0;
    if (idx + 3 < N_NODES) {
      int4 c = *(const int4*)(cnt + idx);
      c0 = c.x; c1 = c.y; c2 = c.z; c3 = c.w;
    } else {
      if (idx     < N_NODES) c0 = cnt[idx];
      if (idx + 1 < N_NODES) c1 = cnt[idx + 1];
      if (idx + 2 < N_NODES) c2 = cnt[idx + 2];
      if (idx + 3 < N_NODES) c3 = cnt[idx + 3];
    }
    int s0 = c0, s01 = s0 + c1, s012 = s01 + c2, tsum = s012 + c3;
    int incl = tsum;
    #pragma unroll
    for (int off = 1; off < 64; off <<= 1) {
      int v = __shfl_up(incl, off, 64);
      if (lane >= off) incl += v;
    }
    if (lane == 63) wsum[wave] = incl;
    __syncthreads();
    if (wave == 0) {
      int v = (lane < 16) ? wsum[lane] : 0;
      int winc = v;
      #pragma unroll
      for (int off = 1; off < 16; off <<= 1) {
        int u = __shfl_up(winc, off, 64);
        if (lane >= off) winc += u;
      }
      if (lane < 16) wsum[lane] = winc - v;   // exclusive
      if (lane == 15) stot = winc;
    }
    __syncthreads();
    int ebase = carry + wsum[wave] + (incl - tsum);
    if (idx     < N_NODES) { rp[idx]     = ebase;        cur[idx]     = ebase; }
    if (idx + 1 < N_NODES) { rp[idx + 1] = ebase + s0;   cur[idx + 1] = ebase + s0; }
    if (idx + 2 < N_NODES) { rp[idx + 2] = ebase + s01;  cur[idx + 2] = ebase + s01; }
    if (idx + 3 < N_NODES) { rp[idx + 3] = ebase + s012; cur[idx + 3] = ebase + s012; }
    carry += stot;
    __syncthreads();
  }
  if (t == 0) rp[N_NODES] = carry;
}

// ---------------- CSR fill, XCD-local dest ranges ----------------
// Each XCD-group scans all edges, placing only dests in its range: scatter region
// per XCD = ~1.6 MB (L2-resident, full-line eviction), cursor atomics L2-local.
__global__ __launch_bounds__(256) void fill_csr(const int* __restrict__ r0, const int* __restrict__ co0, const float* __restrict__ v0,
                                                const int* __restrict__ r1, const int* __restrict__ co1, const float* __restrict__ v1,
                                                int* __restrict__ cur0, int* __restrict__ cur1,
                                                int2* __restrict__ e0, int2* __restrict__ e1) {
  const int nq = N_EDGES / 4;
  const int lo = (int)(blockIdx.x & 7) * NPX;
  const int hi = lo + NPX;
  const int stride = (1024 >> 3) * 256;
  for (int i = (int)(blockIdx.x >> 3) * 256 + threadIdx.x; i < 2 * nq; i += stride) {
    if (i < nq) {
      i32x4 r = __builtin_nontemporal_load((const i32x4*)r0 + i);
      i32x4 c = __builtin_nontemporal_load((const i32x4*)co0 + i);
      f32x4 v = __builtin_nontemporal_load((const f32x4*)v0 + i);
      #pragma unroll
      for (int k = 0; k < 4; ++k) {
        if (r[k] >= lo && r[k] < hi) {
          int p = atomicAdd(&cur0[r[k]], 1);
          e0[p] = make_int2(c[k], __float_as_int(v[k]));
        }
      }
    } else {
      int j = i - nq;
      i32x4 r = __builtin_nontemporal_load((const i32x4*)r1 + j);
      i32x4 c = __builtin_nontemporal_load((const i32x4*)co1 + j);
      f32x4 v = __builtin_nontemporal_load((const f32x4*)v1 + j);
      #pragma unroll
      for (int k = 0; k < 4; ++k) {
        if (r[k] >= lo && r[k] < hi) {
          int p = atomicAdd(&cur1[r[k]], 1);
          e1[p] = make_int2(c[k], __float_as_int(v[k]));
        }
      }
    }
  }
}

// ---------------- SpMM: 1 wave = 1 dest row, full 512 cols, 8 edges in flight ----------------
__global__ __launch_bounds__(256) void spmm_s(const unsigned short* __restrict__ xb,
    const int* __restrict__ rp0, const int2* __restrict__ e0,
    const int* __restrict__ rp1, const int2* __restrict__ e1,
    unsigned short* __restrict__ s) {
  const int t = threadIdx.x;
  const int lane = t & 63;
  const int wave = t >> 6;
  const int n = blockIdx.x * 4 + wave;   // 12500 blocks * 4 waves = 50000 rows
  const int c0 = lane * 8;               // 8 bf16 = 16B per lane

  float acc[2][8] = {};

  #pragma unroll
  for (int sup = 0; sup < 2; ++sup) {
    const int* rp = sup ? rp1 : rp0;
    const int2* e = sup ? e1 : e0;
    float* a = acc[sup];
    const int beg = rp[n], end = rp[n + 1];
    int p = beg;
    for (; p + 7 < end; p += 8) {
      i32x2 m[8];
      u16x8 r[8];
      #pragma unroll
      for (int q = 0; q < 8; ++q) m[q] = *(const i32x2*)(e + p + q);
      #pragma unroll
      for (int q = 0; q < 8; ++q) r[q] = *(const u16x8*)(xb + (size_t)m[q][0] * D + c0);
      #pragma unroll
      for (int q = 0; q < 8; ++q) {
        float v = __int_as_float(m[q][1]);
        #pragma unroll
        for (int i = 0; i < 8; ++i)
          a[i] += v * __uint_as_float(((unsigned)r[q][i]) << 16);
      }
    }
    for (; p < end; ++p) {
      i32x2 m0 = *(const i32x2*)(e + p);
      u16x8 r0 = *(const u16x8*)(xb + (size_t)m0[0] * D + c0);
      float v = __int_as_float(m0[1]);
      #pragma unroll
      for (int i = 0; i < 8; ++i)
        a[i] += v * __uint_as_float(((unsigned)r0[i]) << 16);
    }
  }

  u16x8 o0, o1;
  #pragma unroll
  for (int i = 0; i < 8; ++i) { o0[i] = f2bf(acc[0][i]); o1[i] = f2bf(acc[1][i]); }
  __builtin_nontemporal_store(o0, (u16x8*)(s + (size_t)n * 1024 + c0));
  __builtin_nontemporal_store(o1, (u16x8*)(s + (size_t)n * 1024 + 512 + c0));
}

// ---------------- GEMM: out = relu( s[MPAD][1024] @ Wcat[1024][512] + b ), 2-phase dbuf ----------------
#define BM 128
#define BN 128
#define BK 32

__global__ __launch_bounds__(256) void gemm_out(const unsigned short* __restrict__ s,
                                                const unsigned short* __restrict__ wbT,
                                                const float* __restrict__ bias,
                                                float* __restrict__ out) {
  __shared__ __align__(16) unsigned short As[2][BM * BK];
  __shared__ __align__(16) unsigned short Bs[2][BN * BK];
  const int t = threadIdx.x;
  const int lane = t & 63;
  const int wave = t >> 6;
  const int wm = wave >> 1, wn = wave & 1;
  const int lr = lane & 15;
  const int lk = (lane >> 4) * 8;
  const int m0 = blockIdx.y * BM;
  const int n0 = blockIdx.x * BN;

  f32x4 acc[4][4] = {};
  const int NT = 1024 / BK;   // 32 K-steps

  auto STAGE = [&](int buf, int kt) {
    #pragma unroll
    for (int i = 0; i < 2; ++i) {
      int ch = i * 256 + t;
      int row = ch >> 2;
      int ke = (ch & 3) * 8;
      const unsigned short* ga = s + (size_t)(m0 + row) * 1024 + kt * BK + ke;
      __builtin_amdgcn_global_load_lds(
          (const __attribute__((address_space(1))) unsigned int*)ga,
          (__attribute__((address_space(3))) unsigned int*)(&As[buf][ch * 8]), 16, 0, 0);
      const unsigned short* gb = wbT + (size_t)(n0 + row) * 1024 + kt * BK + ke;
      __builtin_amdgcn_global_load_lds(
          (const __attribute__((address_space(1))) unsigned int*)gb,
          (__attribute__((address_space(3))) unsigned int*)(&Bs[buf][ch * 8]), 16, 0, 0);
    }
  };

  STAGE(0, 0);
  __syncthreads();

  for (int kt = 0; kt < NT; ++kt) {
    const int cur = kt & 1;
    if (kt + 1 < NT) STAGE(cur ^ 1, kt + 1);

    bf16x8 a[4], b[4];
    #pragma unroll
    for (int i = 0; i < 4; ++i)
      a[i] = *(const bf16x8*)&As[cur][(wm * 64 + i * 16 + lr) * BK + lk];
    #pragma unroll
    for (int j = 0; j < 4; ++j)
      b[j] = *(const bf16x8*)&Bs[cur][(wn * 64 + j * 16 + lr) * BK + lk];
    #pragma unroll
    for (int i = 0; i < 4; ++i)
      #pragma unroll
      for (int j = 0; j < 4; ++j)
        acc[i][j] = __builtin_amdgcn_mfma_f32_16x16x32_bf16(a[i], b[j], acc[i][j], 0, 0, 0);
    __syncthreads();
  }

  float bj[4];
  #pragma unroll
  for (int j = 0; j < 4; ++j) bj[j] = bias[n0 + wn * 64 + j * 16 + lr];

  const int orow = (lane >> 4) * 4;
  #pragma unroll
  for (int i = 0; i < 4; ++i) {
    #pragma unroll
    for (int j = 0; j < 4; ++j) {
      #pragma unroll
      for (int r = 0; r < 4; ++r) {
        int row = m0 + wm * 64 + i * 16 + orow + r;
        if (row < N_NODES) {
          int col = n0 + wn * 64 + j * 16 + lr;
          __builtin_nontemporal_store(fmaxf(acc[i][j][r] + bj[j], 0.f),
                                      out + (size_t)row * 512 + col);
        }
      }
    }
  }
}

// ---------------- launch ----------------
extern "C" void kernel_launch(void* const* d_in, const int* in_sizes, int n_in,
                              void* d_out, int out_size, void* d_ws, size_t ws_size,
                              hipStream_t stream) {
  const float* x     = (const float*)d_in[0];
  const float* w0    = (const float*)d_in[1];
  const float* w1    = (const float*)d_in[2];
  const float* bias  = (const float*)d_in[3];
  const float* vals0 = (const float*)d_in[4];
  const float* vals1 = (const float*)d_in[5];
  const int*   rows0 = (const int*)d_in[6];
  const int*   cols0 = (const int*)d_in[7];
  const int*   rows1 = (const int*)d_in[8];
  const int*   cols1 = (const int*)d_in[9];
  float* out = (float*)d_out;

  char* ws = (char*)d_ws;
  size_t off = 0;
  auto alloc = [&](size_t bytes) -> char* {
    char* p = ws + off;
    off += (bytes + 255) & ~(size_t)255;
    return p;
  };
  unsigned short* xb  = (unsigned short*)alloc((size_t)N_NODES * D * 2);   // 51.2 MB
  unsigned short* wbT = (unsigned short*)alloc((size_t)512 * 1024 * 2);    // 1 MB
  unsigned short* s   = (unsigned short*)alloc((size_t)MPAD * 1024 * 2);   // 102.5 MB
  int* rp0  = (int*)alloc((N_NODES + 1) * sizeof(int));
  int* rp1  = (int*)alloc((N_NODES + 1) * sizeof(int));
  int* cur0 = (int*)alloc(N_NODES * sizeof(int));
  int* cur1 = (int*)alloc(N_NODES * sizeof(int));
  int* cnt  = (int*)alloc(2 * N_NODES * sizeof(int));
  int2* e0  = (int2*)alloc((size_t)N_EDGES * sizeof(int2));                // 12.8 MB
  int2* e1  = (int2*)alloc((size_t)N_EDGES * sizeof(int2));                // 12.8 MB

  hipMemsetAsync(cnt, 0, 2 * N_NODES * sizeof(int), stream);
  hipMemsetAsync(s + (size_t)N_NODES * 1024, 0, (size_t)(MPAD - N_NODES) * 1024 * 2, stream);

  convert_x<<<dim3((unsigned)((size_t)N_NODES * D / 8 / 256)), 256, 0, stream>>>(x, xb);
  convert_w<<<dim3(512 * 1024 / 256), 256, 0, stream>>>(w0, w1, wbT);
  histogram<<<1024, 256, 0, stream>>>(rows0, rows1, cnt, cnt + N_NODES);
  scan2<<<2, 1024, 0, stream>>>(cnt, cnt + N_NODES, rp0, rp1, cur0, cur1);
  fill_csr<<<1024, 256, 0, stream>>>(rows0, cols0, vals0, rows1, cols1, vals1,
                                     cur0, cur1, e0, e1);
  spmm_s<<<N_NODES / 4, 256, 0, stream>>>(xb, rp0, e0, rp1, e1, s);
  gemm_out<<<dim3(512 / BN, MPAD / BM), 256, 0, stream>>>(s, wbT, bias, out);
}